// Round 10
// baseline (1852.837 us; speedup 1.0000x reference)
//
#include <hip/hip_runtime.h>
#include <stdint.h>

// CoAttention: emb-gather + GRU(75 steps) + co-attention pool + logits.
// Inputs fp32 in memory (runtime-detected; weights canonicalized to bf16).
//
// ws layout:
//   flag    int           @ 0          (16 B)
//   smalls  bf16[4720]    @ 16         (9472 B)
//   WihImg  bf16          @ 9488       (614400 B)
//   WhhImg  bf16          @ 623888     (614400 B)
//   Wih_c   bf16[270000]  @ 1238288    (540000 B)
//   Whh_c   bf16[270000]  @ 1778288    (540000 B)
//   gxn     fp16          @ 2318288    (15*BC*2560 B slot; 3 PLANES of
//                                       15*BC*320 fp16, reg-packed [m>>2][u][m&3])
//   h_all   bf16          @ +gxn       (75*BC*640 B)
//   hstate  fp32          @ +h         (BC*1280 B)
// BC=2048 total ~182.9 MB (proven budget)
//
// COMPILER FACT (R1/R2/R6): the VGPR cap is an OCCUPANCY-TARGET heuristic.
// 512-thr + small LDS -> capped at 128 (2 WG/CU target). With LDS > 81,920 B
// the compiler knows 1 WG/CU and grants full demand (R9: 640-thr, 143 KB,
// VGPR_Count=80 uncapped). Keep gru LDS > 80 KB when using many registers.
// LAYOUT FACT (R7): gate-packed-by-gate gxn caused 3.3x write amplification;
// planar/reg-packed layouts keep 16-lane groups contiguous.
// R9 FACT: gru time invariant to wave decomposition -> LDS-pipe bound
// (~15K of 25K cy/tt is W through LDS twice). R10 halves it (hybrid W).

typedef float f32x4 __attribute__((ext_vector_type(4)));
typedef short bf16x8 __attribute__((ext_vector_type(8)));
typedef _Float16 f16x4 __attribute__((ext_vector_type(4)));
typedef unsigned short u16;
typedef u16 u16x8 __attribute__((ext_vector_type(8)));
typedef u16 u16x4 __attribute__((ext_vector_type(4)));

#define DI __device__ __forceinline__

DI float bf2f(u16 v) {
    uint32_t u = ((uint32_t)v) << 16;
    float f;
    __builtin_memcpy(&f, &u, 4);
    return f;
}
DI u16 f2bf(float f) {  // round-to-nearest-even
    uint32_t u;
    __builtin_memcpy(&u, &f, 4);
    uint32_t r = u + 0x7fffu + ((u >> 16) & 1u);
    return (u16)(r >> 16);
}
DI u16 cvt1(const void* p, int i, int f32m) {
    return f32m ? f2bf(((const float*)p)[i]) : ((const u16*)p)[i];
}

// bijective per-tile LDS slot swizzle (proven in coattn R5)
DI int hswz(int L, int kt) { return L ^ kt ^ (((L >> 4) & 3) << 1); }

DI u16x8 load_row8(const u16* __restrict__ base, int e0) {
    u16x4 z = {0, 0, 0, 0};
    u16x4 lo = (e0 < 300) ? *(const u16x4*)(base + e0) : z;
    u16x4 hi = (e0 + 4 < 300) ? *(const u16x4*)(base + e0 + 4) : z;
    u16x8 r;
    r[0] = lo[0]; r[1] = lo[1]; r[2] = lo[2]; r[3] = lo[3];
    r[4] = hi[0]; r[5] = hi[1]; r[6] = hi[2]; r[7] = hi[3];
    return r;
}
DI u16x8 load_row8_f32(const float* __restrict__ base, int e0) {
    f32x4 z = {0.f, 0.f, 0.f, 0.f};
    f32x4 lo = (e0 < 300) ? *(const f32x4*)(base + e0) : z;
    f32x4 hi = (e0 + 4 < 300) ? *(const f32x4*)(base + e0 + 4) : z;
    u16x8 r;
    r[0] = f2bf(lo[0]); r[1] = f2bf(lo[1]); r[2] = f2bf(lo[2]); r[3] = f2bf(lo[3]);
    r[4] = f2bf(hi[0]); r[5] = f2bf(hi[1]); r[6] = f2bf(hi[2]); r[7] = f2bf(hi[3]);
    return r;
}

// ---------------------------------------------------------------------------
__global__ __launch_bounds__(256) void detect_dtype(const u16* __restrict__ raw,
                                                    int* __restrict__ flag) {
    __shared__ int cnt;
    if (threadIdx.x == 0) cnt = 0;
    __syncthreads();
    int local = 0;
    for (int i = threadIdx.x; i < 4096; i += 256) {
        int e = (raw[i] >> 7) & 0xFF;
        if (e >= 140) local++;
    }
    atomicAdd(&cnt, local);
    __syncthreads();
    if (threadIdx.x == 0) flag[0] = (cnt > 256) ? 1 : 0;
}

__global__ __launch_bounds__(256) void conv_big(const void* __restrict__ in,
                                                u16* __restrict__ outp, int n,
                                                const int* __restrict__ flag) {
    const int f32m = flag[0];
    int i0 = (blockIdx.x * 256 + threadIdx.x) * 8;
#pragma unroll
    for (int k = 0; k < 8; k++) {
        int i = i0 + k;
        if (i < n) outp[i] = cvt1(in, i, f32m);
    }
}

__global__ __launch_bounds__(256) void conv_smalls(
    const void* bih_r, const void* bhh_r, const void* wCo_r, const void* wCob_r,
    const void* Wmy_r, const void* Wmyb_r, const void* lw_r, const void* lb_r,
    u16* __restrict__ smalls, const int* __restrict__ flag) {
    const int f32m = flag[0];
    int t = blockIdx.x * 256 + threadIdx.x;
    if (t < 900) smalls[t] = cvt1(bih_r, t, f32m);
    else if (t < 1800) smalls[1024 + t - 900] = cvt1(bhh_r, t - 900, f32m);
    else if (t < 2700) smalls[2048 + t - 1800] = cvt1(wCo_r, t - 1800, f32m);
    else if (t < 2775) smalls[3072 + t - 2700] = cvt1(Wmy_r, t - 2700, f32m);
    else if (t < 4275) smalls[3200 + t - 2775] = cvt1(lw_r, t - 2775, f32m);
    else if (t < 4280) smalls[4704 + t - 4275] = cvt1(lb_r, t - 4275, f32m);
    else if (t == 4280) smalls[4712] = cvt1(wCob_r, 0, f32m);
    else if (t == 4281) smalls[4713] = cvt1(Wmyb_r, 0, f32m);
}

// ---------------------------------------------------------------------------
// Pack a (900 x 300) canonical bf16 weight into MFMA B-fragment image:
// img[nt<60][kt<10][lane<64][8], g = nt*16 + (lane&15) in padded 960 space.
// ---------------------------------------------------------------------------
__global__ __launch_bounds__(256) void prep_img(const u16* __restrict__ W,
                                                u16* __restrict__ img) {
    int t = blockIdx.x * 256 + threadIdx.x;
    if (t >= 60 * 10 * 64) return;
    int lane = t & 63;
    int kt = (t >> 6) % 10;
    int nt = t / 640;
    int g = nt * 16 + (lane & 15);
    int gate = g / 320, u = g - gate * 320;
    int e0 = kt * 32 + (lane >> 4) * 8;
    u16x8 v;
    if (u < 300) {
        v = load_row8(W + (size_t)(gate * 300 + u) * 300, e0);
    } else {
        u16x8 z = {0, 0, 0, 0, 0, 0, 0, 0};
        v = z;
    }
    *(u16x8*)&img[(size_t)t * 8] = v;
}

__global__ __launch_bounds__(256) void zero_hstate(float* __restrict__ hs) {
    int t = blockIdx.x * 256 + threadIdx.x;
    f32x4 z = {0.f, 0.f, 0.f, 0.f};
    ((f32x4*)hs)[t] = z;
}

// ---------------------------------------------------------------------------
// GEMM1 — R10: R8 body + reg-packed gxn store: one f16x4 per (mt,nt)
// at gxn[gate*PL + ((mrow>>2)*320 + u)*4 .. +3] (rows q*4..q*4+3 share a
// row-group). 36 vector stores vs 144 scalar; still fully coalesced.
// ---------------------------------------------------------------------------
__global__ __launch_bounds__(256, 2) void gemm1_kernel(
    const int* __restrict__ seq, const void* __restrict__ emb_raw,
    const u16* __restrict__ Wimg, const u16* __restrict__ bih,
    _Float16* __restrict__ gxn, int ck, int phase, int BC, int bshift,
    const int* __restrict__ flag) {
    __shared__ int ids[192];
    __shared__ __align__(16) u16 Aimg[12 * 64 * 8];
    __shared__ __align__(16) u16 Bbuf[12 * 64 * 8];

    const int tid = threadIdx.x;
    const int lane = tid & 63, wv = tid >> 6, q = lane >> 4, c = lane & 15;
    const int m0 = blockIdx.x * 192;
    const int nb = blockIdx.y;
    const int f32m = flag[0];
    const size_t PL = (size_t)15 * BC * 320;  // plane stride (fp16 elems)

    if (tid < 192) {
        int m = m0 + tid;
        int bc = m & (BC - 1);
        int tp = m >> bshift;
        ids[tid] = seq[(size_t)(phase * BC + bc) * 75 + ck * 15 + tp];
    }
    __syncthreads();

    f32x4 acc[3][12];
#pragma unroll
    for (int mt = 0; mt < 3; mt++)
#pragma unroll
        for (int nt = 0; nt < 12; nt++) {
            f32x4 z = {0.f, 0.f, 0.f, 0.f};
            acc[mt][nt] = z;
        }

    for (int kt = 0; kt < 10; kt++) {
#pragma unroll
        for (int s = 0; s < 3; s++) {
            int o = tid + s * 256;
            int qq = o / 192;
            int r = o - qq * 192;
            int e0 = kt * 32 + qq * 8;
            u16x8 v = f32m ? load_row8_f32((const float*)emb_raw + (size_t)ids[r] * 300, e0)
                           : load_row8((const u16*)emb_raw + (size_t)ids[r] * 300, e0);
            *(u16x8*)&Aimg[(((r >> 4) * 64) + ((r & 15) | (qq << 4))) * 8] = v;
        }
#pragma unroll
        for (int s = 0; s < 3; s++) {
            int ch = tid + s * 256;
            *(u16x8*)&Bbuf[ch * 8] =
                *(const u16x8*)&Wimg[(((size_t)(nb * 12 + (ch >> 6)) * 10 + kt) * 64 + (ch & 63)) * 8];
        }
        __syncthreads();

        bf16x8 a[3];
#pragma unroll
        for (int mt = 0; mt < 3; mt++) {
            u16x8 tmp = *(const u16x8*)&Aimg[(((wv * 3 + mt) * 64) + lane) * 8];
            a[mt] = __builtin_bit_cast(bf16x8, tmp);
        }
#pragma unroll
        for (int nt = 0; nt < 12; nt++) {
            u16x8 tb = *(const u16x8*)&Bbuf[(nt * 64 + lane) * 8];
            bf16x8 b = __builtin_bit_cast(bf16x8, tb);
#pragma unroll
            for (int mt = 0; mt < 3; mt++)
                acc[mt][nt] = __builtin_amdgcn_mfma_f32_16x16x32_bf16(a[mt], b, acc[mt][nt], 0, 0, 0);
        }
        __syncthreads();
    }

#pragma unroll
    for (int nt = 0; nt < 12; nt++) {
        int g = nb * 192 + nt * 16 + c;
        int gate = g / 320, u = g - gate * 320;
        float bias = (u < 300) ? bf2f(bih[gate * 300 + u]) : 0.f;
        _Float16* gp = gxn + (size_t)gate * PL;
#pragma unroll
        for (int mt = 0; mt < 3; mt++) {
            int mrow = m0 + (wv * 3 + mt) * 16 + q * 4;  // mrow % 4 == 0
            f16x4 v;
#pragma unroll
            for (int reg = 0; reg < 4; reg++)
                v[reg] = (_Float16)(acc[mt][nt][reg] + bias);
            *(f16x4*)&gp[((size_t)(mrow >> 2) * 320 + u) * 4] = v;
        }
    }
}

// ---------------------------------------------------------------------------
// GRU chunk — R10: hybrid W (half LDS-staged, half register-dbuf) +
// single barrier per tt (H double-buffer) + f16x4 gate loads.
// R9 post-mortem: gru invariant to wave split (149 vs 154) -> LDS-pipe bound
// (~15K of 25K cy/tt = W 600 KB written + 600 KB read through LDS per tt).
// R10: per wave (10 waves x 2 T-tiles), Ti=0's 3 tiles stay in the async
// LDS dbuf; Ti=1's 3 tiles live in a register dbuf wreg[2][3] (full kt
// unroll -> static indices; rule-#20 safe). Halves W LDS traffic.
// LDS = H dbuf 40,960 + W stage 61,440 = 102,400 B: > 81,920 keeps the
// compiler's VGPR budget at the 1-WG/CU level (R6's cap trap avoided),
// demand ~110. Single barrier: gates+FRAG write H[wr] while stragglers
// read H[rd]. vmcnt: per kt 6 vmem (3 lds-dest + 3 reg-dest) + 6 gate
// vec loads at tt top -> kt<2: vmcnt(12); kt>=2: vmcnt(6); last: 0.
// Falsifier: FETCH >> 33 MB or WRITE >> 22 MB => spill => revert hybrid.
// ---------------------------------------------------------------------------
__global__ __launch_bounds__(640, 1) void gru_chunk(
    const _Float16* __restrict__ gxn, const u16* __restrict__ Wimg,
    const u16* __restrict__ bhh_g, u16* __restrict__ h_all,
    float* __restrict__ hstate, int ck, int BC) {
    __shared__ __align__(16) u16 Hhi[2][10 * 64 * 8];  // 2 x 10 KB [buf][kt][lane][8]
    __shared__ __align__(16) u16 Hlo[2][10 * 64 * 8];  // 2 x 10 KB
    __shared__ __align__(16) u16 Wlds[30720];          // 60 KB: wave*3072, buf*1536

    const int tid = threadIdx.x;
    const int lane = tid & 63, wv = tid >> 6, q = lane >> 4, c = lane & 15;
    const int b0 = blockIdx.x * 16;
    const int wbase = wv * 3072;
    const size_t PL = (size_t)15 * BC * 320;  // gxn plane stride

    u16x8 wreg[2][3];  // Ti=1 W tiles, register double-buffer

    // stage one kt-slice: Ti=0 tiles -> LDS (async), Ti=1 tiles -> regs
    auto STAGE = [&](int kt, int buf) {
        u16* dst = &Wlds[wbase + buf * 1536];
#pragma unroll
        for (int g = 0; g < 3; g++) {
            int nt0 = g * 20 + wv;  // Ti=0
            __builtin_amdgcn_global_load_lds(
                (const unsigned int*)(Wimg + (size_t)(nt0 * 10 + kt) * 512 + lane * 8),
                (unsigned int*)(dst + g * 512), 16, 0, 0);
        }
#pragma unroll
        for (int g = 0; g < 3; g++) {
            int nt1 = g * 20 + wv + 10;  // Ti=1
            wreg[buf][g] = *(const u16x8*)&Wimg[(size_t)(nt1 * 10 + kt) * 512 + lane * 8];
        }
    };

    // kt=0 staging ASAP (lands during hstate load + image build; drained by
    // the prologue barrier / compiler reg-deps).
    STAGE(0, 0);

    float bhh[2][3];
    float hm[2][4];
#pragma unroll
    for (int Ti = 0; Ti < 2; Ti++) {
        int T = wv + 10 * Ti;
        int u = T * 16 + c;
#pragma unroll
        for (int g = 0; g < 3; g++)
            bhh[Ti][g] = (u < 300) ? bf2f(bhh_g[g * 300 + u]) : 0.f;
        int kti = T >> 1;
        int qp = ((T & 1) << 1) | (c >> 3);
        int j = c & 7;
#pragma unroll
        for (int reg = 0; reg < 4; reg++) {
            int m = q * 4 + reg;
            float h = hstate[(size_t)(b0 + m) * 320 + u];
            hm[Ti][reg] = h;
            int idx = (kti * 64 + ((q * 4 + reg) | (qp << 4))) * 8 + j;
            u16 hi = f2bf(h);
            Hhi[0][idx] = hi;
            Hlo[0][idx] = f2bf(h - bf2f(hi));
        }
    }
    __syncthreads();

    for (int tt = 0; tt < 15; tt++) {
        const int rd = tt & 1, wr = rd ^ 1;

        // stage kt=1 BEFORE gate loads (vmcnt ordering: W older than gates)
        STAGE(1, 1);

        // gate-input loads: ONE f16x4 per (Ti, gate) covers all 4 regs
        // (reg-packed gxn layout [m>>2][u][m&3])
        f16x4 gv[2][3];
        const size_t rg = ((size_t)tt * BC + b0) >> 2;  // row-group base
#pragma unroll
        for (int Ti = 0; Ti < 2; Ti++) {
            int u = (wv + 10 * Ti) * 16 + c;
            size_t base = ((rg + q) * 320 + u) * 4;
#pragma unroll
            for (int g = 0; g < 3; g++)
                gv[Ti][g] = *(const f16x4*)&gxn[(size_t)g * PL + base];
        }

        f32x4 acc[2][3];
#pragma unroll
        for (int Ti = 0; Ti < 2; Ti++)
#pragma unroll
            for (int g = 0; g < 3; g++) {
                f32x4 z = {0.f, 0.f, 0.f, 0.f};
                acc[Ti][g] = z;
            }

        // gh = (h_hi + h_lo) @ W_hh^T; Ti=0 from LDS dbuf, Ti=1 from wreg.
        // Full unroll so wreg indices are compile-time (rule #20).
#pragma unroll
        for (int kt = 0; kt < 10; kt++) {
            if (kt >= 1 && kt < 9) STAGE(kt + 1, (kt + 1) & 1);
            else if (kt == 9 && tt < 14) STAGE(0, 0);

            if (kt == 9 && tt == 14) {
                asm volatile("s_waitcnt vmcnt(0)" ::: "memory");
            } else if (kt < 2) {
                asm volatile("s_waitcnt vmcnt(12)" ::: "memory");
            } else {
                asm volatile("s_waitcnt vmcnt(6)" ::: "memory");
            }

            u16x8 th = *(const u16x8*)&Hhi[rd][(kt * 64 + lane) * 8];
            u16x8 tl = *(const u16x8*)&Hlo[rd][(kt * 64 + lane) * 8];
            bf16x8 ahi = __builtin_bit_cast(bf16x8, th);
            bf16x8 alo = __builtin_bit_cast(bf16x8, tl);
            const u16* wb = &Wlds[wbase + (kt & 1) * 1536];
#pragma unroll
            for (int g = 0; g < 3; g++) {
                u16x8 tb = *(const u16x8*)&wb[g * 512 + lane * 8];
                bf16x8 b0f = __builtin_bit_cast(bf16x8, tb);
                acc[0][g] = __builtin_amdgcn_mfma_f32_16x16x32_bf16(
                    ahi, b0f, acc[0][g], 0, 0, 0);
                acc[0][g] = __builtin_amdgcn_mfma_f32_16x16x32_bf16(
                    alo, b0f, acc[0][g], 0, 0, 0);
                bf16x8 b1f = __builtin_bit_cast(bf16x8, wreg[kt & 1][g]);
                acc[1][g] = __builtin_amdgcn_mfma_f32_16x16x32_bf16(
                    ahi, b1f, acc[1][g], 0, 0, 0);
                acc[1][g] = __builtin_amdgcn_mfma_f32_16x16x32_bf16(
                    alo, b1f, acc[1][g], 0, 0, 0);
            }
        }

        // Gates + h_all store + write h(t) frags into H[wr] (single barrier)
        const int tglob = ck * 15 + tt;
#pragma unroll
        for (int Ti = 0; Ti < 2; Ti++) {
            int T = wv + 10 * Ti;
            int u = T * 16 + c;
            int kti = T >> 1;
            int qp = ((T & 1) << 1) | (c >> 3);
            int j = c & 7;
#pragma unroll
            for (int reg = 0; reg < 4; reg++) {
                int m = q * 4 + reg;
                float xr = (float)gv[Ti][0][reg];
                float xz = (float)gv[Ti][1][reg];
                float xn = (float)gv[Ti][2][reg];
                float hr = acc[Ti][0][reg] + bhh[Ti][0];
                float hz = acc[Ti][1][reg] + bhh[Ti][1];
                float hn = acc[Ti][2][reg] + bhh[Ti][2];
                float r = 1.f / (1.f + __expf(-(xr + hr)));
                float z = 1.f / (1.f + __expf(-(xz + hz)));
                float ex = __expf(2.f * (xn + r * hn));
                float n = 1.f - 2.f / (ex + 1.f);  // tanh
                float h = (1.f - z) * n + z * hm[Ti][reg];
                hm[Ti][reg] = h;
                h_all[((size_t)tglob * BC + (b0 + m)) * 320 + u] = f2bf(h);
                int idx = (kti * 64 + ((q * 4 + reg) | (qp << 4))) * 8 + j;
                u16 hi = f2bf(h);
                Hhi[wr][idx] = hi;
                Hlo[wr][idx] = f2bf(h - bf2f(hi));
            }
        }
        __syncthreads();  // single barrier: wr visible, rd free for reuse
    }

    // Persist fp32 h state for the next chunk.
#pragma unroll
    for (int Ti = 0; Ti < 2; Ti++) {
        int u = (wv + 10 * Ti) * 16 + c;
#pragma unroll
        for (int reg = 0; reg < 4; reg++) {
            int m = q * 4 + reg;
            hstate[(size_t)(b0 + m) * 320 + u] = hm[Ti][reg];
        }
    }
}

// ---------------------------------------------------------------------------
// Co-attention + pool + logits — R5 structure (proven). Untouched.
// ---------------------------------------------------------------------------
__global__ __launch_bounds__(256) void coattn_kernel(
    const u16* __restrict__ h_all, const u16* __restrict__ smalls,
    void* __restrict__ outv, const int* __restrict__ flag, int phase, int BC) {
    __shared__ __align__(16) u16 himg[5 * 10 * 64 * 8];  // 51,200 B
    __shared__ float smacc[80], aArr[80], bArr[80], diagArr[80], attn[80], smv[80];
    __shared__ float scal[2];
    __shared__ float logitsAcc[5];

    const u16* wCo = smalls + 2048;
    const u16* Wmy = smalls + 3072;
    const u16* lw = smalls + 3200;
    const u16* lb = smalls + 4704;
    const int f32out = flag[0];

    const int b = blockIdx.x;
    const int tid = threadIdx.x;
    const int lane = tid & 63, wv = tid >> 6, q = lane >> 4, c = lane & 15;

    for (int o = tid; o < 3200; o += 256) {
        int i = o / 40;
        int oc = o - i * 40;
        int kt = oc >> 2, qq = oc & 3;
        int e0 = kt * 32 + qq * 8;
        u16x8 v = {0, 0, 0, 0, 0, 0, 0, 0};
        if (i < 75) v = *(const u16x8*)(h_all + ((size_t)i * BC + b) * 320 + e0);
        *(u16x8*)&himg[(((i >> 4) * 10 + kt) * 64 + hswz((i & 15) | (qq << 4), kt)) * 8] = v;
    }
    if (tid < 80) {
        smacc[tid] = 0.f; aArr[tid] = 0.f; bArr[tid] = 0.f;
        diagArr[tid] = 0.f; attn[tid] = 0.f;
    }
    if (tid < 5) logitsAcc[tid] = 0.f;
    __syncthreads();

    for (int pass = 0; pass < 2; pass++) {
        int nt = (pass == 0) ? wv : 4;
        int jj = nt * 16 + c;
        bf16x8 bfr[10];
#pragma unroll
        for (int kt = 0; kt < 10; kt++) {
            int e0 = kt * 32 + q * 8;
            u16x8 res = {0, 0, 0, 0, 0, 0, 0, 0};
            if (jj < 75) {
                u16x8 hv = *(const u16x8*)&himg[((nt * 10 + kt) * 64 + hswz(lane, kt)) * 8];
                u16x8 wcv = load_row8(wCo + 600, e0);
#pragma unroll
                for (int j = 0; j < 8; j++) res[j] = f2bf(bf2f(hv[j]) * bf2f(wcv[j]));
            } else if (jj == 75) {
                res = load_row8(wCo, e0);  // wa
            } else if (jj == 76) {
                res = load_row8(wCo + 300, e0);  // wb
            }
            bfr[kt] = __builtin_bit_cast(bf16x8, res);
        }
        float wmyj = (jj < 75) ? bf2f(Wmy[jj]) : 0.f;

        // pass 0: every wave does all 5 mt for its own nt=wv.
        // pass 1: nt=4 split over waves: w0 -> mt {0,4}; wave w -> mt {w}.
        int nmt = (pass == 0) ? 5 : (wv == 0 ? 2 : 1);
        for (int mi = 0; mi < nmt; mi++) {
            int mt = (pass == 0) ? mi : (wv == 0 ? mi * 4 : wv);
            f32x4 acc = {0.f, 0.f, 0.f, 0.f};
#pragma unroll
            for (int kt = 0; kt < 10; kt++) {
                u16x8 ta = *(const u16x8*)&himg[((mt * 10 + kt) * 64 + hswz(lane, kt)) * 8];
                bf16x8 a = __builtin_bit_cast(bf16x8, ta);
                acc = __builtin_amdgcn_mfma_f32_16x16x32_bf16(a, bfr[kt], acc, 0, 0, 0);
            }
#pragma unroll
            for (int reg = 0; reg < 4; reg++) {
                int i = mt * 16 + q * 4 + reg;
                float v = acc[reg];
                float p = v * wmyj;
                p += __shfl_xor(p, 1);
                p += __shfl_xor(p, 2);
                p += __shfl_xor(p, 4);
                p += __shfl_xor(p, 8);
                if (c == 0 && i < 75) atomicAdd(&smacc[i], p);
                if (jj == i && i < 75) diagArr[i] = v;
                if (jj == 75) aArr[i] = v;
                if (jj == 76) bArr[i] = v;
            }
        }
    }
    __syncthreads();

    if (tid < 64) {
        float w1 = bf2f(Wmy[tid]);
        float w2 = (tid + 64 < 75) ? bf2f(Wmy[tid + 64]) : 0.f;
        float s1 = w1 + w2;
        float s2 = w1 * bArr[tid] + ((tid + 64 < 75) ? w2 * bArr[tid + 64] : 0.f);
#pragma unroll
        for (int m = 1; m < 64; m <<= 1) {
            s1 += __shfl_xor(s1, m);
            s2 += __shfl_xor(s2, m);
        }
        if (tid == 0) { scal[0] = s1; scal[1] = s2; }
    }
    __syncthreads();

    float cb = bf2f(smalls[4712]);
    float wmyb = bf2f(smalls[4713]);
    if (tid < 75) {
        float Wi = bf2f(Wmy[tid]);
        smv[tid] = smacc[tid] - diagArr[tid] * Wi + (aArr[tid] + cb) * (scal[0] - Wi) +
                   scal[1] - bArr[tid] * Wi + wmyb;
    }
    __syncthreads();

    if (tid < 64) {
        float v1 = smv[tid];
        float v2 = (tid + 64 < 75) ? smv[tid + 64] : -1e30f;
        float mx = fmaxf(v1, v2);
#pragma unroll
        for (int m = 1; m < 64; m <<= 1) mx = fmaxf(mx, __shfl_xor(mx, m));
        float e1 = __expf(v1 - mx);
        float e2 = (tid + 64 < 75) ? __expf(v2 - mx) : 0.f;
        float s = e1 + e2;
#pragma unroll
        for (int m = 1; m < 64; m <<= 1) s += __shfl_xor(s, m);
        attn[tid] = e1 / s;
        if (tid + 64 < 75) attn[tid + 64] = e2 / s;
    }
    __syncthreads();

    // pooled in registers from LDS himg (no second h_all global sweep).
    const int d1 = tid, d2 = tid + 256;
    float pd1 = 0.f, pd2 = 0.f;
    {
        const int kt1 = d1 >> 5, qq1 = (d1 >> 3) & 3, j1 = d1 & 7;
        const int kt2 = d2 >> 5, qq2 = (d2 >> 3) & 3, j2 = d2 & 7;
        for (int i = 0; i < 75; i++) {
            float a = attn[i];
            int ih = i >> 4, il = i & 15;
            pd1 += a * bf2f(himg[((ih * 10 + kt1) * 64 + hswz(il | (qq1 << 4), kt1)) * 8 + j1]);
            if (wv == 0)  // wave-uniform branch
                pd2 += a * bf2f(himg[((ih * 10 + kt2) * 64 + hswz(il | (qq2 << 4), kt2)) * 8 + j2]);
        }
    }
#pragma unroll
    for (int o = 0; o < 5; o++) {
        float part = (d1 < 300) ? pd1 * bf2f(lw[o * 300 + d1]) : 0.f;
        if (wv == 0 && d2 < 300) part += pd2 * bf2f(lw[o * 300 + d2]);
#pragma unroll
        for (int m = 1; m < 64; m <<= 1) part += __shfl_xor(part, m);
        if (lane == 0) atomicAdd(&logitsAcc[o], part);
    }
    __syncthreads();

    if (tid < 5) {
        float v = logitsAcc[tid] + bf2f(lb[tid]);
        size_t idx = (size_t)(phase * BC + b) * 5 + tid;
        if (f32out) ((float*)outv)[idx] = v;
        else ((u16*)outv)[idx] = f2bf(v);
    }
}

// ---------------------------------------------------------------------------
extern "C" void kernel_launch(void* const* d_in, const int* in_sizes, int n_in,
                              void* d_out, int out_size, void* d_ws, size_t ws_size,
                              hipStream_t stream) {
    const int* seq = (const int*)d_in[0];

    char* p = (char*)d_ws;
    int* flag = (int*)p;                        // @0
    u16* smalls = (u16*)(p + 16);               // 4720 u16
    u16* WihImg = (u16*)(p + 9488);
    u16* WhhImg = (u16*)(p + 623888);
    u16* Wih_c = (u16*)(p + 1238288);
    u16* Whh_c = (u16*)(p + 1778288);
    const unsigned long long fixed_end = 2318288ull;

    auto req = [&](long long BC) -> unsigned long long {
        return fixed_end + (unsigned long long)BC * 87680ull + 1048576ull;
    };
    int BC = 256, bshift = 8;
    if (ws_size >= req(2048)) { BC = 2048; bshift = 11; }
    else if (ws_size >= req(1024)) { BC = 1024; bshift = 10; }
    else if (ws_size >= req(512)) { BC = 512; bshift = 9; }
    const int P = 2048 / BC;

    unsigned long long gx_b = 15ull * BC * 2560ull;  // slot size (59/78.6 MB used)
    unsigned long long h_b = 75ull * BC * 640ull;
    _Float16* gxn = (_Float16*)(p + fixed_end);
    u16* h_all = (u16*)(p + fixed_end + gx_b);
    float* hstate = (float*)(p + fixed_end + gx_b + h_b);

    detect_dtype<<<dim3(1), dim3(256), 0, stream>>>((const u16*)d_in[1], flag);
    conv_big<<<dim3((270000 + 2047) / 2048), dim3(256), 0, stream>>>(
        d_in[2], Wih_c, 270000, flag);
    conv_big<<<dim3((270000 + 2047) / 2048), dim3(256), 0, stream>>>(
        d_in[3], Whh_c, 270000, flag);
    conv_smalls<<<dim3(17), dim3(256), 0, stream>>>(
        d_in[4], d_in[5], d_in[6], d_in[7], d_in[8], d_in[9], d_in[10], d_in[11],
        smalls, flag);

    prep_img<<<dim3(150), dim3(256), 0, stream>>>(Wih_c, WihImg);
    prep_img<<<dim3(150), dim3(256), 0, stream>>>(Whh_c, WhhImg);

    for (int phase = 0; phase < P; phase++) {
        zero_hstate<<<dim3(BC * 320 / 1024), dim3(256), 0, stream>>>(hstate);
        for (int ck = 0; ck < 5; ck++) {
            gemm1_kernel<<<dim3(15 * BC / 192, 5), dim3(256), 0, stream>>>(
                seq, d_in[1], WihImg, smalls /*bih*/, gxn, ck, phase, BC, bshift, flag);
            gru_chunk<<<dim3(BC / 16), dim3(640), 0, stream>>>(
                gxn, WhhImg, smalls + 1024 /*bhh*/, h_all, hstate, ck, BC);
        }
        coattn_kernel<<<dim3(BC), dim3(256), 0, stream>>>(h_all, smalls, d_out, flag,
                                                          phase, BC);
    }
}

// Round 11
// 1815.048 us; speedup vs baseline: 1.0208x; 1.0208x over previous
//
#include <hip/hip_runtime.h>
#include <stdint.h>

// CoAttention: emb-gather + GRU(75 steps) + co-attention pool + logits.
// Inputs fp32 in memory (runtime-detected; weights canonicalized to bf16).
//
// ws layout:
//   flag    int           @ 0          (16 B)
//   smalls  bf16[4720]    @ 16         (9472 B)
//   WihImg  bf16          @ 9488       (614400 B)
//   WhhImg  bf16          @ 623888     (614400 B)
//   Wih_c   bf16[270000]  @ 1238288    (540000 B)
//   Whh_c   bf16[270000]  @ 1778288    (540000 B)
//   gxn     fp16          @ 2318288    (3 planes of 15*BC*320 fp16,
//                                       reg-packed [m>>2][u][m&3])
//   h_all   bf16          @ +gxn       (75*BC*640 B)
//   hstate  fp32          @ +h         (BC*1280 B)
// BC=2048 total ~182.9 MB (proven budget)
//
// COMPILER FACTS (measured):
//  - VGPR cap is an OCCUPANCY-TARGET heuristic (R1/R2/R6): small-LDS wide
//    WGs get capped (512thr+40KB -> 128). LDS > 81,920 B -> 1 WG/CU budget,
//    full demand granted (R9: 143KB, VGPR 80 uncapped).
//  - R10: array W-regs in a big maybe-unrolled loop -> alloca -> scratch
//    (VGPR 84 + 117 MB extra FETCH = wreg reloaded per tt). R11 uses NAMED
//    registers + literal buffer indices only -- scratch impossible.
// LAYOUT FACT (R7): gate-packed-by-gate gxn caused 3.3x write amplification;
// reg-packed planar layout (R8/R10) keeps 16-lane groups contiguous.
// R9 FACT: gru invariant to wave decomposition -> LDS-pipe bound
// (~half of tt time is W through LDS twice). R11 halves that traffic.

typedef float f32x4 __attribute__((ext_vector_type(4)));
typedef short bf16x8 __attribute__((ext_vector_type(8)));
typedef _Float16 f16x4 __attribute__((ext_vector_type(4)));
typedef unsigned short u16;
typedef u16 u16x8 __attribute__((ext_vector_type(8)));
typedef u16 u16x4 __attribute__((ext_vector_type(4)));

#define DI __device__ __forceinline__

DI float bf2f(u16 v) {
    uint32_t u = ((uint32_t)v) << 16;
    float f;
    __builtin_memcpy(&f, &u, 4);
    return f;
}
DI u16 f2bf(float f) {  // round-to-nearest-even
    uint32_t u;
    __builtin_memcpy(&u, &f, 4);
    uint32_t r = u + 0x7fffu + ((u >> 16) & 1u);
    return (u16)(r >> 16);
}
DI u16 cvt1(const void* p, int i, int f32m) {
    return f32m ? f2bf(((const float*)p)[i]) : ((const u16*)p)[i];
}

// bijective per-tile LDS slot swizzle (proven in coattn R5)
DI int hswz(int L, int kt) { return L ^ kt ^ (((L >> 4) & 3) << 1); }

DI u16x8 load_row8(const u16* __restrict__ base, int e0) {
    u16x4 z = {0, 0, 0, 0};
    u16x4 lo = (e0 < 300) ? *(const u16x4*)(base + e0) : z;
    u16x4 hi = (e0 + 4 < 300) ? *(const u16x4*)(base + e0 + 4) : z;
    u16x8 r;
    r[0] = lo[0]; r[1] = lo[1]; r[2] = lo[2]; r[3] = lo[3];
    r[4] = hi[0]; r[5] = hi[1]; r[6] = hi[2]; r[7] = hi[3];
    return r;
}
DI u16x8 load_row8_f32(const float* __restrict__ base, int e0) {
    f32x4 z = {0.f, 0.f, 0.f, 0.f};
    f32x4 lo = (e0 < 300) ? *(const f32x4*)(base + e0) : z;
    f32x4 hi = (e0 + 4 < 300) ? *(const f32x4*)(base + e0 + 4) : z;
    u16x8 r;
    r[0] = f2bf(lo[0]); r[1] = f2bf(lo[1]); r[2] = f2bf(lo[2]); r[3] = f2bf(lo[3]);
    r[4] = f2bf(hi[0]); r[5] = f2bf(hi[1]); r[6] = f2bf(hi[2]); r[7] = f2bf(hi[3]);
    return r;
}

// ---------------------------------------------------------------------------
__global__ __launch_bounds__(256) void detect_dtype(const u16* __restrict__ raw,
                                                    int* __restrict__ flag) {
    __shared__ int cnt;
    if (threadIdx.x == 0) cnt = 0;
    __syncthreads();
    int local = 0;
    for (int i = threadIdx.x; i < 4096; i += 256) {
        int e = (raw[i] >> 7) & 0xFF;
        if (e >= 140) local++;
    }
    atomicAdd(&cnt, local);
    __syncthreads();
    if (threadIdx.x == 0) flag[0] = (cnt > 256) ? 1 : 0;
}

__global__ __launch_bounds__(256) void conv_big(const void* __restrict__ in,
                                                u16* __restrict__ outp, int n,
                                                const int* __restrict__ flag) {
    const int f32m = flag[0];
    int i0 = (blockIdx.x * 256 + threadIdx.x) * 8;
#pragma unroll
    for (int k = 0; k < 8; k++) {
        int i = i0 + k;
        if (i < n) outp[i] = cvt1(in, i, f32m);
    }
}

__global__ __launch_bounds__(256) void conv_smalls(
    const void* bih_r, const void* bhh_r, const void* wCo_r, const void* wCob_r,
    const void* Wmy_r, const void* Wmyb_r, const void* lw_r, const void* lb_r,
    u16* __restrict__ smalls, const int* __restrict__ flag) {
    const int f32m = flag[0];
    int t = blockIdx.x * 256 + threadIdx.x;
    if (t < 900) smalls[t] = cvt1(bih_r, t, f32m);
    else if (t < 1800) smalls[1024 + t - 900] = cvt1(bhh_r, t - 900, f32m);
    else if (t < 2700) smalls[2048 + t - 1800] = cvt1(wCo_r, t - 1800, f32m);
    else if (t < 2775) smalls[3072 + t - 2700] = cvt1(Wmy_r, t - 2700, f32m);
    else if (t < 4275) smalls[3200 + t - 2775] = cvt1(lw_r, t - 2775, f32m);
    else if (t < 4280) smalls[4704 + t - 4275] = cvt1(lb_r, t - 4275, f32m);
    else if (t == 4280) smalls[4712] = cvt1(wCob_r, 0, f32m);
    else if (t == 4281) smalls[4713] = cvt1(Wmyb_r, 0, f32m);
}

// ---------------------------------------------------------------------------
// Pack a (900 x 300) canonical bf16 weight into MFMA B-fragment image:
// img[nt<60][kt<10][lane<64][8], g = nt*16 + (lane&15) in padded 960 space.
// ---------------------------------------------------------------------------
__global__ __launch_bounds__(256) void prep_img(const u16* __restrict__ W,
                                                u16* __restrict__ img) {
    int t = blockIdx.x * 256 + threadIdx.x;
    if (t >= 60 * 10 * 64) return;
    int lane = t & 63;
    int kt = (t >> 6) % 10;
    int nt = t / 640;
    int g = nt * 16 + (lane & 15);
    int gate = g / 320, u = g - gate * 320;
    int e0 = kt * 32 + (lane >> 4) * 8;
    u16x8 v;
    if (u < 300) {
        v = load_row8(W + (size_t)(gate * 300 + u) * 300, e0);
    } else {
        u16x8 z = {0, 0, 0, 0, 0, 0, 0, 0};
        v = z;
    }
    *(u16x8*)&img[(size_t)t * 8] = v;
}

__global__ __launch_bounds__(256) void zero_hstate(float* __restrict__ hs) {
    int t = blockIdx.x * 256 + threadIdx.x;
    f32x4 z = {0.f, 0.f, 0.f, 0.f};
    ((f32x4*)hs)[t] = z;
}

// ---------------------------------------------------------------------------
// GEMM1 — R10 proven: per-kt A staging (25 KB LDS, 2 WG/CU) + reg-packed
// planar gxn store: one f16x4 per (mt,nt) at gxn[gate*PL+((m>>2)*320+u)*4].
// Untouched.
// ---------------------------------------------------------------------------
__global__ __launch_bounds__(256, 2) void gemm1_kernel(
    const int* __restrict__ seq, const void* __restrict__ emb_raw,
    const u16* __restrict__ Wimg, const u16* __restrict__ bih,
    _Float16* __restrict__ gxn, int ck, int phase, int BC, int bshift,
    const int* __restrict__ flag) {
    __shared__ int ids[192];
    __shared__ __align__(16) u16 Aimg[12 * 64 * 8];
    __shared__ __align__(16) u16 Bbuf[12 * 64 * 8];

    const int tid = threadIdx.x;
    const int lane = tid & 63, wv = tid >> 6, q = lane >> 4, c = lane & 15;
    const int m0 = blockIdx.x * 192;
    const int nb = blockIdx.y;
    const int f32m = flag[0];
    const size_t PL = (size_t)15 * BC * 320;  // plane stride (fp16 elems)

    if (tid < 192) {
        int m = m0 + tid;
        int bc = m & (BC - 1);
        int tp = m >> bshift;
        ids[tid] = seq[(size_t)(phase * BC + bc) * 75 + ck * 15 + tp];
    }
    __syncthreads();

    f32x4 acc[3][12];
#pragma unroll
    for (int mt = 0; mt < 3; mt++)
#pragma unroll
        for (int nt = 0; nt < 12; nt++) {
            f32x4 z = {0.f, 0.f, 0.f, 0.f};
            acc[mt][nt] = z;
        }

    for (int kt = 0; kt < 10; kt++) {
#pragma unroll
        for (int s = 0; s < 3; s++) {
            int o = tid + s * 256;
            int qq = o / 192;
            int r = o - qq * 192;
            int e0 = kt * 32 + qq * 8;
            u16x8 v = f32m ? load_row8_f32((const float*)emb_raw + (size_t)ids[r] * 300, e0)
                           : load_row8((const u16*)emb_raw + (size_t)ids[r] * 300, e0);
            *(u16x8*)&Aimg[(((r >> 4) * 64) + ((r & 15) | (qq << 4))) * 8] = v;
        }
#pragma unroll
        for (int s = 0; s < 3; s++) {
            int ch = tid + s * 256;
            *(u16x8*)&Bbuf[ch * 8] =
                *(const u16x8*)&Wimg[(((size_t)(nb * 12 + (ch >> 6)) * 10 + kt) * 64 + (ch & 63)) * 8];
        }
        __syncthreads();

        bf16x8 a[3];
#pragma unroll
        for (int mt = 0; mt < 3; mt++) {
            u16x8 tmp = *(const u16x8*)&Aimg[(((wv * 3 + mt) * 64) + lane) * 8];
            a[mt] = __builtin_bit_cast(bf16x8, tmp);
        }
#pragma unroll
        for (int nt = 0; nt < 12; nt++) {
            u16x8 tb = *(const u16x8*)&Bbuf[(nt * 64 + lane) * 8];
            bf16x8 b = __builtin_bit_cast(bf16x8, tb);
#pragma unroll
            for (int mt = 0; mt < 3; mt++)
                acc[mt][nt] = __builtin_amdgcn_mfma_f32_16x16x32_bf16(a[mt], b, acc[mt][nt], 0, 0, 0);
        }
        __syncthreads();
    }

#pragma unroll
    for (int nt = 0; nt < 12; nt++) {
        int g = nb * 192 + nt * 16 + c;
        int gate = g / 320, u = g - gate * 320;
        float bias = (u < 300) ? bf2f(bih[gate * 300 + u]) : 0.f;
        _Float16* gp = gxn + (size_t)gate * PL;
#pragma unroll
        for (int mt = 0; mt < 3; mt++) {
            int mrow = m0 + (wv * 3 + mt) * 16 + q * 4;  // mrow % 4 == 0
            f16x4 v;
#pragma unroll
            for (int reg = 0; reg < 4; reg++)
                v[reg] = (_Float16)(acc[mt][nt][reg] + bias);
            *(f16x4*)&gp[((size_t)(mrow >> 2) * 320 + u) * 4] = v;
        }
    }
}

// ---------------------------------------------------------------------------
// GRU chunk — R11: hybrid W with SCRATCH-PROOF named registers.
// R10 failed because array wreg[buf] in a maybe-unrolled loop became an
// alloca (VGPR 84, +117 MB scratch FETCH). R11: six NAMED u16x8 (wE0..2 /
// wO0..2), kt loop hand-paired even/odd so every buffer index is a literal
// -- scratch is structurally impossible regardless of unrolling.
// Per wave (10 waves x 2 T-tiles): Ti=0's 3 tiles via async LDS dbuf,
// Ti=1's 3 tiles via the named reg dbuf -> halves W LDS traffic (the R9
// bottleneck). Each stage = 6 vmem ops (3 lds-dest + 3 reg-dest); every
// body: {stage other-parity; vmcnt(6); compute} (kp0-A: vmcnt(12) defers
// gate drain; final body: vmcnt(0)).
// LDS = H 20,480 + Wlds 62,464 (padded) = 82,944 B > 81,920 -> 1 WG/CU
// budget -> full VGPR demand granted (cap-trap guard).
// Falsifier: VGPR <= 90 AND FETCH > 50 MB => scratch again => revert.
// ---------------------------------------------------------------------------
#define WTILE(g_, kt_) \
    (*(const u16x8*)&Wimg[((size_t)(((g_)*20 + wv + 10) * 10 + (kt_))) * 512 + lane * 8])

#define STAGE_LDS(kt_, buf_)                                                      \
    {                                                                             \
        u16* dst_ = &Wlds[wbase + (buf_)*1536];                                   \
        _Pragma("unroll") for (int g_ = 0; g_ < 3; g_++) {                        \
            int nt_ = g_ * 20 + wv;                                               \
            __builtin_amdgcn_global_load_lds(                                     \
                (const unsigned int*)(Wimg + (size_t)(nt_ * 10 + (kt_)) * 512 +   \
                                      lane * 8),                                  \
                (unsigned int*)(dst_ + g_ * 512), 16, 0, 0);                      \
        }                                                                         \
    }

#define COMPUTE(kt_, buf_, w0_, w1_, w2_)                                         \
    {                                                                             \
        u16x8 th_ = *(const u16x8*)&Hhi[((kt_)*64 + lane) * 8];                   \
        u16x8 tl_ = *(const u16x8*)&Hlo[((kt_)*64 + lane) * 8];                   \
        bf16x8 ahi_ = __builtin_bit_cast(bf16x8, th_);                            \
        bf16x8 alo_ = __builtin_bit_cast(bf16x8, tl_);                            \
        const u16* wb_ = &Wlds[wbase + (buf_)*1536];                              \
        _Pragma("unroll") for (int g_ = 0; g_ < 3; g_++) {                        \
            u16x8 tb_ = *(const u16x8*)&wb_[g_ * 512 + lane * 8];                 \
            bf16x8 b0_ = __builtin_bit_cast(bf16x8, tb_);                         \
            acc[0][g_] = __builtin_amdgcn_mfma_f32_16x16x32_bf16(                 \
                ahi_, b0_, acc[0][g_], 0, 0, 0);                                  \
            acc[0][g_] = __builtin_amdgcn_mfma_f32_16x16x32_bf16(                 \
                alo_, b0_, acc[0][g_], 0, 0, 0);                                  \
        }                                                                         \
        bf16x8 b10_ = __builtin_bit_cast(bf16x8, w0_);                            \
        acc[1][0] = __builtin_amdgcn_mfma_f32_16x16x32_bf16(ahi_, b10_,           \
                                                            acc[1][0], 0, 0, 0); \
        acc[1][0] = __builtin_amdgcn_mfma_f32_16x16x32_bf16(alo_, b10_,           \
                                                            acc[1][0], 0, 0, 0); \
        bf16x8 b11_ = __builtin_bit_cast(bf16x8, w1_);                            \
        acc[1][1] = __builtin_amdgcn_mfma_f32_16x16x32_bf16(ahi_, b11_,           \
                                                            acc[1][1], 0, 0, 0); \
        acc[1][1] = __builtin_amdgcn_mfma_f32_16x16x32_bf16(alo_, b11_,           \
                                                            acc[1][1], 0, 0, 0); \
        bf16x8 b12_ = __builtin_bit_cast(bf16x8, w2_);                            \
        acc[1][2] = __builtin_amdgcn_mfma_f32_16x16x32_bf16(ahi_, b12_,           \
                                                            acc[1][2], 0, 0, 0); \
        acc[1][2] = __builtin_amdgcn_mfma_f32_16x16x32_bf16(alo_, b12_,           \
                                                            acc[1][2], 0, 0, 0); \
    }

__global__ __launch_bounds__(640, 1) void gru_chunk(
    const _Float16* __restrict__ gxn, const u16* __restrict__ Wimg,
    const u16* __restrict__ bhh_g, u16* __restrict__ h_all,
    float* __restrict__ hstate, int ck, int BC) {
    __shared__ __align__(16) u16 Hhi[10 * 64 * 8];  // 10 KB [kt][lane][8]
    __shared__ __align__(16) u16 Hlo[10 * 64 * 8];  // 10 KB
    __shared__ __align__(16) u16 Wlds[31232];       // 62,464 B (60 KB used + pad
                                                    // to keep total LDS > 80 KB)

    const int tid = threadIdx.x;
    const int lane = tid & 63, wv = tid >> 6, q = lane >> 4, c = lane & 15;
    const int b0 = blockIdx.x * 16;
    const int wbase = wv * 3072;
    const size_t PL = (size_t)15 * BC * 320;  // gxn plane stride

    // Ti=1 W tiles: named register double-buffer (scratch-proof)
    u16x8 wE0, wE1, wE2, wO0, wO1, wO2;

    // kt=0 staging ASAP (even parity -> E); drained by the prologue barrier
    // (LDS part) / register dependencies (reg part).
    STAGE_LDS(0, 0);
    wE0 = WTILE(0, 0); wE1 = WTILE(1, 0); wE2 = WTILE(2, 0);

    float bhh[2][3];
    float hm[2][4];
#pragma unroll
    for (int Ti = 0; Ti < 2; Ti++) {
        int T = wv + 10 * Ti;
        int u = T * 16 + c;
#pragma unroll
        for (int g = 0; g < 3; g++)
            bhh[Ti][g] = (u < 300) ? bf2f(bhh_g[g * 300 + u]) : 0.f;
        int kti = T >> 1;
        int qp = ((T & 1) << 1) | (c >> 3);
        int j = c & 7;
#pragma unroll
        for (int reg = 0; reg < 4; reg++) {
            int m = q * 4 + reg;
            float h = hstate[(size_t)(b0 + m) * 320 + u];
            hm[Ti][reg] = h;
            int idx = (kti * 64 + ((q * 4 + reg) | (qp << 4))) * 8 + j;
            u16 hi = f2bf(h);
            Hhi[idx] = hi;
            Hlo[idx] = f2bf(h - bf2f(hi));
        }
    }
    __syncthreads();

    for (int tt = 0; tt < 15; tt++) {
        // gate-input loads: ONE f16x4 per (Ti, gate) (reg-packed gxn layout)
        f16x4 gv[2][3];
        const size_t rg = ((size_t)tt * BC + b0) >> 2;  // row-group base
#pragma unroll
        for (int Ti = 0; Ti < 2; Ti++) {
            int u = (wv + 10 * Ti) * 16 + c;
            size_t base = ((rg + q) * 320 + u) * 4;
#pragma unroll
            for (int g = 0; g < 3; g++)
                gv[Ti][g] = *(const f16x4*)&gxn[(size_t)g * PL + base];
        }

        f32x4 acc[2][3];
#pragma unroll
        for (int Ti = 0; Ti < 2; Ti++)
#pragma unroll
            for (int g = 0; g < 3; g++) {
                f32x4 z = {0.f, 0.f, 0.f, 0.f};
                acc[Ti][g] = z;
            }

        // Paired kt loop: even body uses E buffers, odd body uses O buffers.
        // All buffer indices are LITERALS -- no alloca possible.
#pragma unroll
        for (int kp = 0; kp < 5; kp++) {
            const int ktA = 2 * kp, ktB = 2 * kp + 1;

            // body A (compute ktA from E): stage ktB -> O
            STAGE_LDS(ktB, 1);
            wO0 = WTILE(0, ktB); wO1 = WTILE(1, ktB); wO2 = WTILE(2, ktB);
            if (kp == 0) {
                // outstanding: 6 gates + 6 O-stage; E data predates the
                // barrier -> nothing to drain (defer gate drain to body B)
                asm volatile("s_waitcnt vmcnt(12)" ::: "memory");
            } else {
                // drain prev body B's E-stage (= ktA data); leave O-stage
                asm volatile("s_waitcnt vmcnt(6)" ::: "memory");
            }
            COMPUTE(ktA, 0, wE0, wE1, wE2);

            // body B (compute ktB from O): stage ktB+1 (or next-tt kt0) -> E
            if (ktB < 9) {
                STAGE_LDS(ktB + 1, 0);
                wE0 = WTILE(0, ktB + 1); wE1 = WTILE(1, ktB + 1); wE2 = WTILE(2, ktB + 1);
                asm volatile("s_waitcnt vmcnt(6)" ::: "memory");  // drain O (+gates at kp0)
            } else if (tt < 14) {
                STAGE_LDS(0, 0);
                wE0 = WTILE(0, 0); wE1 = WTILE(1, 0); wE2 = WTILE(2, 0);
                asm volatile("s_waitcnt vmcnt(6)" ::: "memory");
            } else {
                asm volatile("s_waitcnt vmcnt(0)" ::: "memory");  // final slice
            }
            COMPUTE(ktB, 1, wO0, wO1, wO2);
        }

        // Gates (C layout col=lane&15 -> u, row=q*4+reg -> m)
        const int tglob = ck * 15 + tt;
#pragma unroll
        for (int Ti = 0; Ti < 2; Ti++) {
            int u = (wv + 10 * Ti) * 16 + c;
#pragma unroll
            for (int reg = 0; reg < 4; reg++) {
                int m = q * 4 + reg;
                float xr = (float)gv[Ti][0][reg];
                float xz = (float)gv[Ti][1][reg];
                float xn = (float)gv[Ti][2][reg];
                float hr = acc[Ti][0][reg] + bhh[Ti][0];
                float hz = acc[Ti][1][reg] + bhh[Ti][1];
                float hn = acc[Ti][2][reg] + bhh[Ti][2];
                float r = 1.f / (1.f + __expf(-(xr + hr)));
                float z = 1.f / (1.f + __expf(-(xz + hz)));
                float ex = __expf(2.f * (xn + r * hn));
                float n = 1.f - 2.f / (ex + 1.f);  // tanh
                float h = (1.f - z) * n + z * hm[Ti][reg];
                hm[Ti][reg] = h;
                h_all[((size_t)tglob * BC + (b0 + m)) * 320 + u] = f2bf(h);
            }
        }
        __syncthreads();  // all fragment reads of h(t-1) done

        // Write new h into fragment images (hi + lo)
#pragma unroll
        for (int Ti = 0; Ti < 2; Ti++) {
            int T = wv + 10 * Ti;
            int kti = T >> 1;
            int qp = ((T & 1) << 1) | (c >> 3);
            int j = c & 7;
#pragma unroll
            for (int reg = 0; reg < 4; reg++) {
                int idx = (kti * 64 + ((q * 4 + reg) | (qp << 4))) * 8 + j;
                float h = hm[Ti][reg];
                u16 hi = f2bf(h);
                Hhi[idx] = hi;
                Hlo[idx] = f2bf(h - bf2f(hi));
            }
        }
        __syncthreads();
    }

    // Persist fp32 h state for the next chunk.
#pragma unroll
    for (int Ti = 0; Ti < 2; Ti++) {
        int u = (wv + 10 * Ti) * 16 + c;
#pragma unroll
        for (int reg = 0; reg < 4; reg++) {
            int m = q * 4 + reg;
            hstate[(size_t)(b0 + m) * 320 + u] = hm[Ti][reg];
        }
    }
}

// ---------------------------------------------------------------------------
// Co-attention + pool + logits — R5 structure (proven). Untouched.
// ---------------------------------------------------------------------------
__global__ __launch_bounds__(256) void coattn_kernel(
    const u16* __restrict__ h_all, const u16* __restrict__ smalls,
    void* __restrict__ outv, const int* __restrict__ flag, int phase, int BC) {
    __shared__ __align__(16) u16 himg[5 * 10 * 64 * 8];  // 51,200 B
    __shared__ float smacc[80], aArr[80], bArr[80], diagArr[80], attn[80], smv[80];
    __shared__ float scal[2];
    __shared__ float logitsAcc[5];

    const u16* wCo = smalls + 2048;
    const u16* Wmy = smalls + 3072;
    const u16* lw = smalls + 3200;
    const u16* lb = smalls + 4704;
    const int f32out = flag[0];

    const int b = blockIdx.x;
    const int tid = threadIdx.x;
    const int lane = tid & 63, wv = tid >> 6, q = lane >> 4, c = lane & 15;

    for (int o = tid; o < 3200; o += 256) {
        int i = o / 40;
        int oc = o - i * 40;
        int kt = oc >> 2, qq = oc & 3;
        int e0 = kt * 32 + qq * 8;
        u16x8 v = {0, 0, 0, 0, 0, 0, 0, 0};
        if (i < 75) v = *(const u16x8*)(h_all + ((size_t)i * BC + b) * 320 + e0);
        *(u16x8*)&himg[(((i >> 4) * 10 + kt) * 64 + hswz((i & 15) | (qq << 4), kt)) * 8] = v;
    }
    if (tid < 80) {
        smacc[tid] = 0.f; aArr[tid] = 0.f; bArr[tid] = 0.f;
        diagArr[tid] = 0.f; attn[tid] = 0.f;
    }
    if (tid < 5) logitsAcc[tid] = 0.f;
    __syncthreads();

    for (int pass = 0; pass < 2; pass++) {
        int nt = (pass == 0) ? wv : 4;
        int jj = nt * 16 + c;
        bf16x8 bfr[10];
#pragma unroll
        for (int kt = 0; kt < 10; kt++) {
            int e0 = kt * 32 + q * 8;
            u16x8 res = {0, 0, 0, 0, 0, 0, 0, 0};
            if (jj < 75) {
                u16x8 hv = *(const u16x8*)&himg[((nt * 10 + kt) * 64 + hswz(lane, kt)) * 8];
                u16x8 wcv = load_row8(wCo + 600, e0);
#pragma unroll
                for (int j = 0; j < 8; j++) res[j] = f2bf(bf2f(hv[j]) * bf2f(wcv[j]));
            } else if (jj == 75) {
                res = load_row8(wCo, e0);  // wa
            } else if (jj == 76) {
                res = load_row8(wCo + 300, e0);  // wb
            }
            bfr[kt] = __builtin_bit_cast(bf16x8, res);
        }
        float wmyj = (jj < 75) ? bf2f(Wmy[jj]) : 0.f;

        // pass 0: every wave does all 5 mt for its own nt=wv.
        // pass 1: nt=4 split over waves: w0 -> mt {0,4}; wave w -> mt {w}.
        int nmt = (pass == 0) ? 5 : (wv == 0 ? 2 : 1);
        for (int mi = 0; mi < nmt; mi++) {
            int mt = (pass == 0) ? mi : (wv == 0 ? mi * 4 : wv);
            f32x4 acc = {0.f, 0.f, 0.f, 0.f};
#pragma unroll
            for (int kt = 0; kt < 10; kt++) {
                u16x8 ta = *(const u16x8*)&himg[((mt * 10 + kt) * 64 + hswz(lane, kt)) * 8];
                bf16x8 a = __builtin_bit_cast(bf16x8, ta);
                acc = __builtin_amdgcn_mfma_f32_16x16x32_bf16(a, bfr[kt], acc, 0, 0, 0);
            }
#pragma unroll
            for (int reg = 0; reg < 4; reg++) {
                int i = mt * 16 + q * 4 + reg;
                float v = acc[reg];
                float p = v * wmyj;
                p += __shfl_xor(p, 1);
                p += __shfl_xor(p, 2);
                p += __shfl_xor(p, 4);
                p += __shfl_xor(p, 8);
                if (c == 0 && i < 75) atomicAdd(&smacc[i], p);
                if (jj == i && i < 75) diagArr[i] = v;
                if (jj == 75) aArr[i] = v;
                if (jj == 76) bArr[i] = v;
            }
        }
    }
    __syncthreads();

    if (tid < 64) {
        float w1 = bf2f(Wmy[tid]);
        float w2 = (tid + 64 < 75) ? bf2f(Wmy[tid + 64]) : 0.f;
        float s1 = w1 + w2;
        float s2 = w1 * bArr[tid] + ((tid + 64 < 75) ? w2 * bArr[tid + 64] : 0.f);
#pragma unroll
        for (int m = 1; m < 64; m <<= 1) {
            s1 += __shfl_xor(s1, m);
            s2 += __shfl_xor(s2, m);
        }
        if (tid == 0) { scal[0] = s1; scal[1] = s2; }
    }
    __syncthreads();

    float cb = bf2f(smalls[4712]);
    float wmyb = bf2f(smalls[4713]);
    if (tid < 75) {
        float Wi = bf2f(Wmy[tid]);
        smv[tid] = smacc[tid] - diagArr[tid] * Wi + (aArr[tid] + cb) * (scal[0] - Wi) +
                   scal[1] - bArr[tid] * Wi + wmyb;
    }
    __syncthreads();

    if (tid < 64) {
        float v1 = smv[tid];
        float v2 = (tid + 64 < 75) ? smv[tid + 64] : -1e30f;
        float mx = fmaxf(v1, v2);
#pragma unroll
        for (int m = 1; m < 64; m <<= 1) mx = fmaxf(mx, __shfl_xor(mx, m));
        float e1 = __expf(v1 - mx);
        float e2 = (tid + 64 < 75) ? __expf(v2 - mx) : 0.f;
        float s = e1 + e2;
#pragma unroll
        for (int m = 1; m < 64; m <<= 1) s += __shfl_xor(s, m);
        attn[tid] = e1 / s;
        if (tid + 64 < 75) attn[tid + 64] = e2 / s;
    }
    __syncthreads();

    // pooled in registers from LDS himg (no second h_all global sweep).
    const int d1 = tid, d2 = tid + 256;
    float pd1 = 0.f, pd2 = 0.f;
    {
        const int kt1 = d1 >> 5, qq1 = (d1 >> 3) & 3, j1 = d1 & 7;
        const int kt2 = d2 >> 5, qq2 = (d2 >> 3) & 3, j2 = d2 & 7;
        for (int i = 0; i < 75; i++) {
            float a = attn[i];
            int ih = i >> 4, il = i & 15;
            pd1 += a * bf2f(himg[((ih * 10 + kt1) * 64 + hswz(il | (qq1 << 4), kt1)) * 8 + j1]);
            if (wv == 0)  // wave-uniform branch
                pd2 += a * bf2f(himg[((ih * 10 + kt2) * 64 + hswz(il | (qq2 << 4), kt2)) * 8 + j2]);
        }
    }
#pragma unroll
    for (int o = 0; o < 5; o++) {
        float part = (d1 < 300) ? pd1 * bf2f(lw[o * 300 + d1]) : 0.f;
        if (wv == 0 && d2 < 300) part += pd2 * bf2f(lw[o * 300 + d2]);
#pragma unroll
        for (int m = 1; m < 64; m <<= 1) part += __shfl_xor(part, m);
        if (lane == 0) atomicAdd(&logitsAcc[o], part);
    }
    __syncthreads();

    if (tid < 5) {
        float v = logitsAcc[tid] + bf2f(lb[tid]);
        size_t idx = (size_t)(phase * BC + b) * 5 + tid;
        if (f32out) ((float*)outv)[idx] = v;
        else ((u16*)outv)[idx] = f2bf(v);
    }
}

// ---------------------------------------------------------------------------
extern "C" void kernel_launch(void* const* d_in, const int* in_sizes, int n_in,
                              void* d_out, int out_size, void* d_ws, size_t ws_size,
                              hipStream_t stream) {
    const int* seq = (const int*)d_in[0];

    char* p = (char*)d_ws;
    int* flag = (int*)p;                        // @0
    u16* smalls = (u16*)(p + 16);               // 4720 u16
    u16* WihImg = (u16*)(p + 9488);
    u16* WhhImg = (u16*)(p + 623888);
    u16* Wih_c = (u16*)(p + 1238288);
    u16* Whh_c = (u16*)(p + 1778288);
    const unsigned long long fixed_end = 2318288ull;

    auto req = [&](long long BC) -> unsigned long long {
        return fixed_end + (unsigned long long)BC * 87680ull + 1048576ull;
    };
    int BC = 256, bshift = 8;
    if (ws_size >= req(2048)) { BC = 2048; bshift = 11; }
    else if (ws_size >= req(1024)) { BC = 1024; bshift = 10; }
    else if (ws_size >= req(512)) { BC = 512; bshift = 9; }
    const int P = 2048 / BC;

    unsigned long long gx_b = 15ull * BC * 2560ull;  // slot size (59/78.6 MB used)
    unsigned long long h_b = 75ull * BC * 640ull;
    _Float16* gxn = (_Float16*)(p + fixed_end);
    u16* h_all = (u16*)(p + fixed_end + gx_b);
    float* hstate = (float*)(p + fixed_end + gx_b + h_b);

    detect_dtype<<<dim3(1), dim3(256), 0, stream>>>((const u16*)d_in[1], flag);
    conv_big<<<dim3((270000 + 2047) / 2048), dim3(256), 0, stream>>>(
        d_in[2], Wih_c, 270000, flag);
    conv_big<<<dim3((270000 + 2047) / 2048), dim3(256), 0, stream>>>(
        d_in[3], Whh_c, 270000, flag);
    conv_smalls<<<dim3(17), dim3(256), 0, stream>>>(
        d_in[4], d_in[5], d_in[6], d_in[7], d_in[8], d_in[9], d_in[10], d_in[11],
        smalls, flag);

    prep_img<<<dim3(150), dim3(256), 0, stream>>>(Wih_c, WihImg);
    prep_img<<<dim3(150), dim3(256), 0, stream>>>(Whh_c, WhhImg);

    for (int phase = 0; phase < P; phase++) {
        zero_hstate<<<dim3(BC * 320 / 1024), dim3(256), 0, stream>>>(hstate);
        for (int ck = 0; ck < 5; ck++) {
            gemm1_kernel<<<dim3(15 * BC / 192, 5), dim3(256), 0, stream>>>(
                seq, d_in[1], WihImg, smalls /*bih*/, gxn, ck, phase, BC, bshift, flag);
            gru_chunk<<<dim3(BC / 16), dim3(640), 0, stream>>>(
                gxn, WhhImg, smalls + 1024 /*bhh*/, h_all, hstate, ck, BC);
        }
        coattn_kernel<<<dim3(BC), dim3(256), 0, stream>>>(h_all, smalls, d_out, flag,
                                                          phase, BC);
    }
}

// Round 12
// 1257.581 us; speedup vs baseline: 1.4733x; 1.4433x over previous
//
#include <hip/hip_runtime.h>
#include <stdint.h>

// CoAttention: emb-gather + GRU(75 steps) + co-attention pool + logits.
// Inputs fp32 in memory (runtime-detected; weights canonicalized to bf16).
//
// ws layout:
//   flag    int           @ 0          (16 B)
//   smalls  bf16[4720]    @ 16         (9472 B)
//   WihImg  bf16          @ 9488       (614400 B)
//   WhhImg  bf16          @ 623888     (614400 B)
//   Wih_c   bf16[270000]  @ 1238288    (540000 B)
//   Whh_c   bf16[270000]  @ 1778288    (540000 B)
//   gxn     fp16          @ 2318288    (3 planes of 15*BC*320 fp16,
//                                       reg-packed [m>>2][u][m&3])
//   h_all   bf16          @ +gxn       (75*BC*640 B)
//   hstate  fp32          @ +h         (BC*1280 B)
// BC=2048 total ~182.9 MB (proven budget)
//
// COMPILER FACT (FINAL, R1/R2/R6/R10/R11 — 5x measured): hipcc's per-thread
// VGPR budget is a hard function of BLOCK SIZE ONLY (occupancy-target
// heuristic; __launch_bounds__ min-blocks and LDS size DO NOT lift it):
//   256-thr -> 256   512-thr -> 128   640-thr -> 84
// Demand above the cap => scratch spill (R6: 430us; R10/R11: +90-120 MB
// FETCH). W-in-registers at wide blocks is structurally impossible.
// LAYOUT FACT (R7): gate-interleaved gxn caused 3.3x HBM write
// amplification; planar/reg-packed (R8/R10) fixed it.
// R9 FACT: gru time invariant to wave decomposition (balance not binding).

typedef float f32x4 __attribute__((ext_vector_type(4)));
typedef short bf16x8 __attribute__((ext_vector_type(8)));
typedef _Float16 f16x4 __attribute__((ext_vector_type(4)));
typedef unsigned short u16;
typedef u16 u16x8 __attribute__((ext_vector_type(8)));
typedef u16 u16x4 __attribute__((ext_vector_type(4)));

#define DI __device__ __forceinline__

template <int N> struct IC { static constexpr int v = N; };

DI float bf2f(u16 v) {
    uint32_t u = ((uint32_t)v) << 16;
    float f;
    __builtin_memcpy(&f, &u, 4);
    return f;
}
DI u16 f2bf(float f) {  // round-to-nearest-even
    uint32_t u;
    __builtin_memcpy(&u, &f, 4);
    uint32_t r = u + 0x7fffu + ((u >> 16) & 1u);
    return (u16)(r >> 16);
}
DI u16 cvt1(const void* p, int i, int f32m) {
    return f32m ? f2bf(((const float*)p)[i]) : ((const u16*)p)[i];
}

// bijective per-tile LDS slot swizzle (proven R5/R7; involution since the
// qq-bits (L>>4) are untouched by the XORs)
DI int hswz(int L, int kt) { return L ^ kt ^ (((L >> 4) & 3) << 1); }

DI u16x8 load_row8(const u16* __restrict__ base, int e0) {
    u16x4 z = {0, 0, 0, 0};
    u16x4 lo = (e0 < 300) ? *(const u16x4*)(base + e0) : z;
    u16x4 hi = (e0 + 4 < 300) ? *(const u16x4*)(base + e0 + 4) : z;
    u16x8 r;
    r[0] = lo[0]; r[1] = lo[1]; r[2] = lo[2]; r[3] = lo[3];
    r[4] = hi[0]; r[5] = hi[1]; r[6] = hi[2]; r[7] = hi[3];
    return r;
}
DI u16x8 load_row8_f32(const float* __restrict__ base, int e0) {
    f32x4 z = {0.f, 0.f, 0.f, 0.f};
    f32x4 lo = (e0 < 300) ? *(const f32x4*)(base + e0) : z;
    f32x4 hi = (e0 + 4 < 300) ? *(const f32x4*)(base + e0 + 4) : z;
    u16x8 r;
    r[0] = f2bf(lo[0]); r[1] = f2bf(lo[1]); r[2] = f2bf(lo[2]); r[3] = f2bf(lo[3]);
    r[4] = f2bf(hi[0]); r[5] = f2bf(hi[1]); r[6] = f2bf(hi[2]); r[7] = f2bf(hi[3]);
    return r;
}

// ---------------------------------------------------------------------------
__global__ __launch_bounds__(256) void detect_dtype(const u16* __restrict__ raw,
                                                    int* __restrict__ flag) {
    __shared__ int cnt;
    if (threadIdx.x == 0) cnt = 0;
    __syncthreads();
    int local = 0;
    for (int i = threadIdx.x; i < 4096; i += 256) {
        int e = (raw[i] >> 7) & 0xFF;
        if (e >= 140) local++;
    }
    atomicAdd(&cnt, local);
    __syncthreads();
    if (threadIdx.x == 0) flag[0] = (cnt > 256) ? 1 : 0;
}

__global__ __launch_bounds__(256) void conv_big(const void* __restrict__ in,
                                                u16* __restrict__ outp, int n,
                                                const int* __restrict__ flag) {
    const int f32m = flag[0];
    int i0 = (blockIdx.x * 256 + threadIdx.x) * 8;
#pragma unroll
    for (int k = 0; k < 8; k++) {
        int i = i0 + k;
        if (i < n) outp[i] = cvt1(in, i, f32m);
    }
}

__global__ __launch_bounds__(256) void conv_smalls(
    const void* bih_r, const void* bhh_r, const void* wCo_r, const void* wCob_r,
    const void* Wmy_r, const void* Wmyb_r, const void* lw_r, const void* lb_r,
    u16* __restrict__ smalls, const int* __restrict__ flag) {
    const int f32m = flag[0];
    int t = blockIdx.x * 256 + threadIdx.x;
    if (t < 900) smalls[t] = cvt1(bih_r, t, f32m);
    else if (t < 1800) smalls[1024 + t - 900] = cvt1(bhh_r, t - 900, f32m);
    else if (t < 2700) smalls[2048 + t - 1800] = cvt1(wCo_r, t - 1800, f32m);
    else if (t < 2775) smalls[3072 + t - 2700] = cvt1(Wmy_r, t - 2700, f32m);
    else if (t < 4275) smalls[3200 + t - 2775] = cvt1(lw_r, t - 2775, f32m);
    else if (t < 4280) smalls[4704 + t - 4275] = cvt1(lb_r, t - 4275, f32m);
    else if (t == 4280) smalls[4712] = cvt1(wCob_r, 0, f32m);
    else if (t == 4281) smalls[4713] = cvt1(Wmyb_r, 0, f32m);
}

// ---------------------------------------------------------------------------
// Pack a (900 x 300) canonical bf16 weight into MFMA B-fragment image:
// img[nt<60][kt<10][lane<64][8], g = nt*16 + (lane&15) in padded 960 space.
// ---------------------------------------------------------------------------
__global__ __launch_bounds__(256) void prep_img(const u16* __restrict__ W,
                                                u16* __restrict__ img) {
    int t = blockIdx.x * 256 + threadIdx.x;
    if (t >= 60 * 10 * 64) return;
    int lane = t & 63;
    int kt = (t >> 6) % 10;
    int nt = t / 640;
    int g = nt * 16 + (lane & 15);
    int gate = g / 320, u = g - gate * 320;
    int e0 = kt * 32 + (lane >> 4) * 8;
    u16x8 v;
    if (u < 300) {
        v = load_row8(W + (size_t)(gate * 300 + u) * 300, e0);
    } else {
        u16x8 z = {0, 0, 0, 0, 0, 0, 0, 0};
        v = z;
    }
    *(u16x8*)&img[(size_t)t * 8] = v;
}

__global__ __launch_bounds__(256) void zero_hstate(float* __restrict__ hs) {
    int t = blockIdx.x * 256 + threadIdx.x;
    f32x4 z = {0.f, 0.f, 0.f, 0.f};
    ((f32x4*)hs)[t] = z;
}

// ---------------------------------------------------------------------------
// GEMM1 — R12: HALF-K A-image. Pre-R12 the kernel re-gathered the same 192
// emb rows from L3 once per kt (10x, 2.3 MB/WG, 1.84 GB/launch). R7's
// full-K image (123 KB LDS) dropped occupancy 2->1 WG/CU and regressed.
// R12: stage 5 kt-slices at a time (61,440 B); LDS total 74.5 KB < 81,920
// -> 2 WG/CU KEPT, emb gathered only 2x (-80% L3 traffic).
// Stores stay reg-packed planar (f16x4, write amp ~1x).
// ---------------------------------------------------------------------------
__global__ __launch_bounds__(256, 2) void gemm1_kernel(
    const int* __restrict__ seq, const void* __restrict__ emb_raw,
    const u16* __restrict__ Wimg, const u16* __restrict__ bih,
    _Float16* __restrict__ gxn, int ck, int phase, int BC, int bshift,
    const int* __restrict__ flag) {
    __shared__ int ids[192];
    __shared__ __align__(16) u16 Aimg[12 * 5 * 64 * 8];  // 61,440 B [mt][k5][64][8]
    __shared__ __align__(16) u16 Bbuf[12 * 64 * 8];      // 12,288 B

    const int tid = threadIdx.x;
    const int lane = tid & 63, wv = tid >> 6, q = lane >> 4, c = lane & 15;
    const int m0 = blockIdx.x * 192;
    const int nb = blockIdx.y;
    const int f32m = flag[0];
    const size_t PL = (size_t)15 * BC * 320;  // plane stride (fp16 elems)

    if (tid < 192) {
        int m = m0 + tid;
        int bc = m & (BC - 1);
        int tp = m >> bshift;
        ids[tid] = seq[(size_t)(phase * BC + bc) * 75 + ck * 15 + tp];
    }
    __syncthreads();

    f32x4 acc[3][12];
#pragma unroll
    for (int mt = 0; mt < 3; mt++)
#pragma unroll
        for (int nt = 0; nt < 12; nt++) {
            f32x4 z = {0.f, 0.f, 0.f, 0.f};
            acc[mt][nt] = z;
        }

    for (int half = 0; half < 2; half++) {
        // stage A for 5 kt-slices (15 iters/thread); prev half's reads are
        // closed by the last kt's post-MFMA barrier.
        for (int o = tid; o < 3840; o += 256) {
            int k5 = o / 768;
            int rem = o - k5 * 768;
            int qq = rem / 192;
            int r = rem - qq * 192;
            int ktg = half * 5 + k5;
            int e0 = ktg * 32 + qq * 8;
            u16x8 v = f32m ? load_row8_f32((const float*)emb_raw + (size_t)ids[r] * 300, e0)
                           : load_row8((const u16*)emb_raw + (size_t)ids[r] * 300, e0);
            *(u16x8*)&Aimg[(((r >> 4) * 5 + k5) * 64 + hswz((r & 15) | (qq << 4), ktg)) * 8] = v;
        }
        __syncthreads();

        for (int k5 = 0; k5 < 5; k5++) {
            const int ktg = half * 5 + k5;
#pragma unroll
            for (int s = 0; s < 3; s++) {
                int ch = tid + s * 256;
                *(u16x8*)&Bbuf[ch * 8] =
                    *(const u16x8*)&Wimg[(((size_t)(nb * 12 + (ch >> 6)) * 10 + ktg) * 64 + (ch & 63)) * 8];
            }
            __syncthreads();

            bf16x8 a[3];
#pragma unroll
            for (int mt = 0; mt < 3; mt++) {
                u16x8 tmp = *(const u16x8*)&Aimg[(((wv * 3 + mt) * 5 + k5) * 64 + hswz(lane, ktg)) * 8];
                a[mt] = __builtin_bit_cast(bf16x8, tmp);
            }
#pragma unroll
            for (int nt = 0; nt < 12; nt++) {
                u16x8 tb = *(const u16x8*)&Bbuf[(nt * 64 + lane) * 8];
                bf16x8 b = __builtin_bit_cast(bf16x8, tb);
#pragma unroll
                for (int mt = 0; mt < 3; mt++)
                    acc[mt][nt] = __builtin_amdgcn_mfma_f32_16x16x32_bf16(a[mt], b, acc[mt][nt], 0, 0, 0);
            }
            __syncthreads();
        }
    }

#pragma unroll
    for (int nt = 0; nt < 12; nt++) {
        int g = nb * 192 + nt * 16 + c;
        int gate = g / 320, u = g - gate * 320;
        float bias = (u < 300) ? bf2f(bih[gate * 300 + u]) : 0.f;
        _Float16* gp = gxn + (size_t)gate * PL;
#pragma unroll
        for (int mt = 0; mt < 3; mt++) {
            int mrow = m0 + (wv * 3 + mt) * 16 + q * 4;  // mrow % 4 == 0
            f16x4 v;
#pragma unroll
            for (int reg = 0; reg < 4; reg++)
                v[reg] = (_Float16)(acc[mt][nt][reg] + bias);
            *(f16x4*)&gp[((size_t)(mrow >> 2) * 320 + u) * 4] = v;
        }
    }
}

// ---------------------------------------------------------------------------
// GRU chunk — R12: exact R8 structure (proven 149 us, VGPR 108, no spill):
// 512 thr / 8 waves, wave-private async LDS W staging (120 KB), counted
// vmcnt(9)/(6), Hhi/Hlo single-buffered, 2 barriers/tt.
// Only delta vs R8: gate inputs via f16x4 from reg-packed gxn (9/6 vector
// loads vs 24/16 scalar; vmcnt accounting unchanged: gates+stores drained
// by the kt=0 wait, stage slice stays in flight).
// W-in-register variants are DEAD (block-size VGPR cap, see header).
// ---------------------------------------------------------------------------
__global__ __launch_bounds__(512, 1) void gru_chunk(
    const _Float16* __restrict__ gxn, const u16* __restrict__ Wimg,
    const u16* __restrict__ bhh_g, u16* __restrict__ h_all,
    float* __restrict__ hstate, int ck, int BC) {
    __shared__ __align__(16) u16 Hhi[10 * 64 * 8];  // 10 KB [kt][lane][8]
    __shared__ __align__(16) u16 Hlo[10 * 64 * 8];  // 10 KB
    __shared__ __align__(16) u16 Wlds[61440];       // 120 KB staging (uneven split)

    const int tid = threadIdx.x;
    const int lane = tid & 63, wv = tid >> 6, q = lane >> 4, c = lane & 15;
    const int b0 = blockIdx.x * 16;
    const int wbase = (wv < 4) ? wv * 9216 : 36864 + (wv - 4) * 6144;
    const size_t PL = (size_t)15 * BC * 320;  // gxn plane stride

    float bhh[3][3];
    float hm[3][4];

    // stage one kt-slice of this wave's tiles into buffer `buf`
    auto STAGE = [&](int kt, int buf, auto NTIC) {
        constexpr int NTI = NTIC.v;
        u16* dst = &Wlds[wbase + buf * (NTI * 3 * 512)];
#pragma unroll
        for (int Ti = 0; Ti < NTI; Ti++)
#pragma unroll
            for (int g = 0; g < 3; g++) {
                int nt = g * 20 + (wv + 8 * Ti);
                __builtin_amdgcn_global_load_lds(
                    (const unsigned int*)(Wimg + (size_t)(nt * 10 + kt) * 512 + lane * 8),
                    (unsigned int*)(dst + (Ti * 3 + g) * 512), 16, 0, 0);
            }
    };

    // issue kt=0 staging ASAP (lands during hstate load + image build)
    if (wv < 4) STAGE(0, 0, IC<3>{}); else STAGE(0, 0, IC<2>{});

    auto INIT = [&](auto NTIC) {
        constexpr int NTI = NTIC.v;
#pragma unroll
        for (int Ti = 0; Ti < NTI; Ti++) {
            int T = wv + 8 * Ti;
            int u = T * 16 + c;
#pragma unroll
            for (int g = 0; g < 3; g++)
                bhh[Ti][g] = (u < 300) ? bf2f(bhh_g[g * 300 + u]) : 0.f;
            int kti = T >> 1;
            int qp = ((T & 1) << 1) | (c >> 3);
            int j = c & 7;
#pragma unroll
            for (int reg = 0; reg < 4; reg++) {
                int m = q * 4 + reg;
                float h = hstate[(size_t)(b0 + m) * 320 + u];
                hm[Ti][reg] = h;
                int idx = (kti * 64 + ((q * 4 + reg) | (qp << 4))) * 8 + j;
                u16 hi = f2bf(h);
                Hhi[idx] = hi;
                Hlo[idx] = f2bf(h - bf2f(hi));
            }
        }
    };
    if (wv < 4) INIT(IC<3>{}); else INIT(IC<2>{});
    __syncthreads();

    for (int tt = 0; tt < 15; tt++) {
        auto PH1 = [&](auto NTIC) {
            constexpr int NTI = NTIC.v;
            // gate-input loads: ONE f16x4 per (Ti, gate) (reg-packed gxn)
            f16x4 gv[NTI][3];
            const size_t rg = ((size_t)tt * BC + b0) >> 2;  // row-group base
#pragma unroll
            for (int Ti = 0; Ti < NTI; Ti++) {
                int u = (wv + 8 * Ti) * 16 + c;
                size_t base = ((rg + q) * 320 + u) * 4;
#pragma unroll
                for (int g = 0; g < 3; g++)
                    gv[Ti][g] = *(const f16x4*)&gxn[(size_t)g * PL + base];
            }

            f32x4 acc[NTI][3];
#pragma unroll
            for (int Ti = 0; Ti < NTI; Ti++)
#pragma unroll
                for (int g = 0; g < 3; g++) {
                    f32x4 z = {0.f, 0.f, 0.f, 0.f};
                    acc[Ti][g] = z;
                }

            // gh = (h_hi + h_lo) @ W_hh^T, W via wave-private async LDS dbuf
#pragma unroll 2
            for (int kt = 0; kt < 10; kt++) {
                if (kt < 9) STAGE(kt + 1, (kt + 1) & 1, NTIC);
                else if (tt < 14) STAGE(0, 0, NTIC);
                // newest NT3 outstanding vmem = just-issued stage; waiting
                // to NT3 drains current slice + gates + prev-tt stores.
                if (kt == 9 && tt == 14) {
                    asm volatile("s_waitcnt vmcnt(0)" ::: "memory");
                } else if constexpr (NTIC.v == 3) {
                    asm volatile("s_waitcnt vmcnt(9)" ::: "memory");
                } else {
                    asm volatile("s_waitcnt vmcnt(6)" ::: "memory");
                }

                u16x8 th = *(const u16x8*)&Hhi[(kt * 64 + lane) * 8];
                u16x8 tl = *(const u16x8*)&Hlo[(kt * 64 + lane) * 8];
                bf16x8 ahi = __builtin_bit_cast(bf16x8, th);
                bf16x8 alo = __builtin_bit_cast(bf16x8, tl);
                const u16* wb = &Wlds[wbase + (kt & 1) * (NTI * 3 * 512)];
#pragma unroll
                for (int Ti = 0; Ti < NTI; Ti++)
#pragma unroll
                    for (int g = 0; g < 3; g++) {
                        u16x8 tb = *(const u16x8*)&wb[(Ti * 3 + g) * 512 + lane * 8];
                        bf16x8 b = __builtin_bit_cast(bf16x8, tb);
                        acc[Ti][g] = __builtin_amdgcn_mfma_f32_16x16x32_bf16(
                            ahi, b, acc[Ti][g], 0, 0, 0);
                        acc[Ti][g] = __builtin_amdgcn_mfma_f32_16x16x32_bf16(
                            alo, b, acc[Ti][g], 0, 0, 0);
                    }
            }

            // Gates (C layout col=lane&15 -> u, row=q*4+reg -> m)
            const int tglob = ck * 15 + tt;
#pragma unroll
            for (int Ti = 0; Ti < NTI; Ti++) {
                int u = (wv + 8 * Ti) * 16 + c;
#pragma unroll
                for (int reg = 0; reg < 4; reg++) {
                    int m = q * 4 + reg;
                    float xr = (float)gv[Ti][0][reg];
                    float xz = (float)gv[Ti][1][reg];
                    float xn = (float)gv[Ti][2][reg];
                    float hr = acc[Ti][0][reg] + bhh[Ti][0];
                    float hz = acc[Ti][1][reg] + bhh[Ti][1];
                    float hn = acc[Ti][2][reg] + bhh[Ti][2];
                    float r = 1.f / (1.f + __expf(-(xr + hr)));
                    float z = 1.f / (1.f + __expf(-(xz + hz)));
                    float ex = __expf(2.f * (xn + r * hn));
                    float n = 1.f - 2.f / (ex + 1.f);  // tanh
                    float h = (1.f - z) * n + z * hm[Ti][reg];
                    hm[Ti][reg] = h;
                    h_all[((size_t)tglob * BC + (b0 + m)) * 320 + u] = f2bf(h);
                }
            }
        };
        if (wv < 4) PH1(IC<3>{}); else PH1(IC<2>{});
        __syncthreads();  // all fragment reads of h(t-1) done

        auto FRAG = [&](auto NTIC) {
            constexpr int NTI = NTIC.v;
#pragma unroll
            for (int Ti = 0; Ti < NTI; Ti++) {
                int T = wv + 8 * Ti;
                int kti = T >> 1;
                int qp = ((T & 1) << 1) | (c >> 3);
                int j = c & 7;
#pragma unroll
                for (int reg = 0; reg < 4; reg++) {
                    int idx = (kti * 64 + ((q * 4 + reg) | (qp << 4))) * 8 + j;
                    float h = hm[Ti][reg];
                    u16 hi = f2bf(h);
                    Hhi[idx] = hi;
                    Hlo[idx] = f2bf(h - bf2f(hi));
                }
            }
        };
        if (wv < 4) FRAG(IC<3>{}); else FRAG(IC<2>{});
        __syncthreads();
    }

    // Persist fp32 h state for the next chunk.
    auto PERSIST = [&](auto NTIC) {
        constexpr int NTI = NTIC.v;
#pragma unroll
        for (int Ti = 0; Ti < NTI; Ti++) {
            int u = (wv + 8 * Ti) * 16 + c;
#pragma unroll
            for (int reg = 0; reg < 4; reg++) {
                int m = q * 4 + reg;
                hstate[(size_t)(b0 + m) * 320 + u] = hm[Ti][reg];
            }
        }
    };
    if (wv < 4) PERSIST(IC<3>{}); else PERSIST(IC<2>{});
}

// ---------------------------------------------------------------------------
// Co-attention + pool + logits — R5 structure (proven). Untouched.
// ---------------------------------------------------------------------------
__global__ __launch_bounds__(256) void coattn_kernel(
    const u16* __restrict__ h_all, const u16* __restrict__ smalls,
    void* __restrict__ outv, const int* __restrict__ flag, int phase, int BC) {
    __shared__ __align__(16) u16 himg[5 * 10 * 64 * 8];  // 51,200 B
    __shared__ float smacc[80], aArr[80], bArr[80], diagArr[80], attn[80], smv[80];
    __shared__ float scal[2];
    __shared__ float logitsAcc[5];

    const u16* wCo = smalls + 2048;
    const u16* Wmy = smalls + 3072;
    const u16* lw = smalls + 3200;
    const u16* lb = smalls + 4704;
    const int f32out = flag[0];

    const int b = blockIdx.x;
    const int tid = threadIdx.x;
    const int lane = tid & 63, wv = tid >> 6, q = lane >> 4, c = lane & 15;

    for (int o = tid; o < 3200; o += 256) {
        int i = o / 40;
        int oc = o - i * 40;
        int kt = oc >> 2, qq = oc & 3;
        int e0 = kt * 32 + qq * 8;
        u16x8 v = {0, 0, 0, 0, 0, 0, 0, 0};
        if (i < 75) v = *(const u16x8*)(h_all + ((size_t)i * BC + b) * 320 + e0);
        *(u16x8*)&himg[(((i >> 4) * 10 + kt) * 64 + hswz((i & 15) | (qq << 4), kt)) * 8] = v;
    }
    if (tid < 80) {
        smacc[tid] = 0.f; aArr[tid] = 0.f; bArr[tid] = 0.f;
        diagArr[tid] = 0.f; attn[tid] = 0.f;
    }
    if (tid < 5) logitsAcc[tid] = 0.f;
    __syncthreads();

    for (int pass = 0; pass < 2; pass++) {
        int nt = (pass == 0) ? wv : 4;
        int jj = nt * 16 + c;
        bf16x8 bfr[10];
#pragma unroll
        for (int kt = 0; kt < 10; kt++) {
            int e0 = kt * 32 + q * 8;
            u16x8 res = {0, 0, 0, 0, 0, 0, 0, 0};
            if (jj < 75) {
                u16x8 hv = *(const u16x8*)&himg[((nt * 10 + kt) * 64 + hswz(lane, kt)) * 8];
                u16x8 wcv = load_row8(wCo + 600, e0);
#pragma unroll
                for (int j = 0; j < 8; j++) res[j] = f2bf(bf2f(hv[j]) * bf2f(wcv[j]));
            } else if (jj == 75) {
                res = load_row8(wCo, e0);  // wa
            } else if (jj == 76) {
                res = load_row8(wCo + 300, e0);  // wb
            }
            bfr[kt] = __builtin_bit_cast(bf16x8, res);
        }
        float wmyj = (jj < 75) ? bf2f(Wmy[jj]) : 0.f;

        // pass 0: every wave does all 5 mt for its own nt=wv.
        // pass 1: nt=4 split over waves: w0 -> mt {0,4}; wave w -> mt {w}.
        int nmt = (pass == 0) ? 5 : (wv == 0 ? 2 : 1);
        for (int mi = 0; mi < nmt; mi++) {
            int mt = (pass == 0) ? mi : (wv == 0 ? mi * 4 : wv);
            f32x4 acc = {0.f, 0.f, 0.f, 0.f};
#pragma unroll
            for (int kt = 0; kt < 10; kt++) {
                u16x8 ta = *(const u16x8*)&himg[((mt * 10 + kt) * 64 + hswz(lane, kt)) * 8];
                bf16x8 a = __builtin_bit_cast(bf16x8, ta);
                acc = __builtin_amdgcn_mfma_f32_16x16x32_bf16(a, bfr[kt], acc, 0, 0, 0);
            }
#pragma unroll
            for (int reg = 0; reg < 4; reg++) {
                int i = mt * 16 + q * 4 + reg;
                float v = acc[reg];
                float p = v * wmyj;
                p += __shfl_xor(p, 1);
                p += __shfl_xor(p, 2);
                p += __shfl_xor(p, 4);
                p += __shfl_xor(p, 8);
                if (c == 0 && i < 75) atomicAdd(&smacc[i], p);
                if (jj == i && i < 75) diagArr[i] = v;
                if (jj == 75) aArr[i] = v;
                if (jj == 76) bArr[i] = v;
            }
        }
    }
    __syncthreads();

    if (tid < 64) {
        float w1 = bf2f(Wmy[tid]);
        float w2 = (tid + 64 < 75) ? bf2f(Wmy[tid + 64]) : 0.f;
        float s1 = w1 + w2;
        float s2 = w1 * bArr[tid] + ((tid + 64 < 75) ? w2 * bArr[tid + 64] : 0.f);
#pragma unroll
        for (int m = 1; m < 64; m <<= 1) {
            s1 += __shfl_xor(s1, m);
            s2 += __shfl_xor(s2, m);
        }
        if (tid == 0) { scal[0] = s1; scal[1] = s2; }
    }
    __syncthreads();

    float cb = bf2f(smalls[4712]);
    float wmyb = bf2f(smalls[4713]);
    if (tid < 75) {
        float Wi = bf2f(Wmy[tid]);
        smv[tid] = smacc[tid] - diagArr[tid] * Wi + (aArr[tid] + cb) * (scal[0] - Wi) +
                   scal[1] - bArr[tid] * Wi + wmyb;
    }
    __syncthreads();

    if (tid < 64) {
        float v1 = smv[tid];
        float v2 = (tid + 64 < 75) ? smv[tid + 64] : -1e30f;
        float mx = fmaxf(v1, v2);
#pragma unroll
        for (int m = 1; m < 64; m <<= 1) mx = fmaxf(mx, __shfl_xor(mx, m));
        float e1 = __expf(v1 - mx);
        float e2 = (tid + 64 < 75) ? __expf(v2 - mx) : 0.f;
        float s = e1 + e2;
#pragma unroll
        for (int m = 1; m < 64; m <<= 1) s += __shfl_xor(s, m);
        attn[tid] = e1 / s;
        if (tid + 64 < 75) attn[tid + 64] = e2 / s;
    }
    __syncthreads();

    // pooled in registers from LDS himg (no second h_all global sweep).
    const int d1 = tid, d2 = tid + 256;
    float pd1 = 0.f, pd2 = 0.f;
    {
        const int kt1 = d1 >> 5, qq1 = (d1 >> 3) & 3, j1 = d1 & 7;
        const int kt2 = d2 >> 5, qq2 = (d2 >> 3) & 3, j2 = d2 & 7;
        for (int i = 0; i < 75; i++) {
            float a = attn[i];
            int ih = i >> 4, il = i & 15;
            pd1 += a * bf2f(himg[((ih * 10 + kt1) * 64 + hswz(il | (qq1 << 4), kt1)) * 8 + j1]);
            if (wv == 0)  // wave-uniform branch
                pd2 += a * bf2f(himg[((ih * 10 + kt2) * 64 + hswz(il | (qq2 << 4), kt2)) * 8 + j2]);
        }
    }
#pragma unroll
    for (int o = 0; o < 5; o++) {
        float part = (d1 < 300) ? pd1 * bf2f(lw[o * 300 + d1]) : 0.f;
        if (wv == 0 && d2 < 300) part += pd2 * bf2f(lw[o * 300 + d2]);
#pragma unroll
        for (int m = 1; m < 64; m <<= 1) part += __shfl_xor(part, m);
        if (lane == 0) atomicAdd(&logitsAcc[o], part);
    }
    __syncthreads();

    if (tid < 5) {
        float v = logitsAcc[tid] + bf2f(lb[tid]);
        size_t idx = (size_t)(phase * BC + b) * 5 + tid;
        if (f32out) ((float*)outv)[idx] = v;
        else ((u16*)outv)[idx] = f2bf(v);
    }
}

// ---------------------------------------------------------------------------
extern "C" void kernel_launch(void* const* d_in, const int* in_sizes, int n_in,
                              void* d_out, int out_size, void* d_ws, size_t ws_size,
                              hipStream_t stream) {
    const int* seq = (const int*)d_in[0];

    char* p = (char*)d_ws;
    int* flag = (int*)p;                        // @0
    u16* smalls = (u16*)(p + 16);               // 4720 u16
    u16* WihImg = (u16*)(p + 9488);
    u16* WhhImg = (u16*)(p + 623888);
    u16* Wih_c = (u16*)(p + 1238288);
    u16* Whh_c = (u16*)(p + 1778288);
    const unsigned long long fixed_end = 2318288ull;

    auto req = [&](long long BC) -> unsigned long long {
        return fixed_end + (unsigned long long)BC * 87680ull + 1048576ull;
    };
    int BC = 256, bshift = 8;
    if (ws_size >= req(2048)) { BC = 2048; bshift = 11; }
    else if (ws_size >= req(1024)) { BC = 1024; bshift = 10; }
    else if (ws_size >= req(512)) { BC = 512; bshift = 9; }
    const int P = 2048 / BC;

    unsigned long long gx_b = 15ull * BC * 2560ull;  // slot size (59/78.6 MB used)
    unsigned long long h_b = 75ull * BC * 640ull;
    _Float16* gxn = (_Float16*)(p + fixed_end);
    u16* h_all = (u16*)(p + fixed_end + gx_b);
    float* hstate = (float*)(p + fixed_end + gx_b + h_b);

    detect_dtype<<<dim3(1), dim3(256), 0, stream>>>((const u16*)d_in[1], flag);
    conv_big<<<dim3((270000 + 2047) / 2048), dim3(256), 0, stream>>>(
        d_in[2], Wih_c, 270000, flag);
    conv_big<<<dim3((270000 + 2047) / 2048), dim3(256), 0, stream>>>(
        d_in[3], Whh_c, 270000, flag);
    conv_smalls<<<dim3(17), dim3(256), 0, stream>>>(
        d_in[4], d_in[5], d_in[6], d_in[7], d_in[8], d_in[9], d_in[10], d_in[11],
        smalls, flag);

    prep_img<<<dim3(150), dim3(256), 0, stream>>>(Wih_c, WihImg);
    prep_img<<<dim3(150), dim3(256), 0, stream>>>(Whh_c, WhhImg);

    for (int phase = 0; phase < P; phase++) {
        zero_hstate<<<dim3(BC * 320 / 1024), dim3(256), 0, stream>>>(hstate);
        for (int ck = 0; ck < 5; ck++) {
            gemm1_kernel<<<dim3(15 * BC / 192, 5), dim3(256), 0, stream>>>(
                seq, d_in[1], WihImg, smalls /*bih*/, gxn, ck, phase, BC, bshift, flag);
            gru_chunk<<<dim3(BC / 16), dim3(512), 0, stream>>>(
                gxn, WhhImg, smalls + 1024 /*bhh*/, h_all, hstate, ck, BC);
        }
        coattn_kernel<<<dim3(BC), dim3(256), 0, stream>>>(h_all, smalls, d_out, flag,
                                                          phase, BC);
    }
}